// Round 10
// baseline (247.498 us; speedup 1.0000x reference)
//
#include <hip/hip_runtime.h>
#include <hip/hip_bf16.h>
#include <math.h>

#define NH   12
#define HD   64
#define HID  768
#define NB   4
#define SS   2048
#define MR   (NB*SS)   // 8192 rows

#define NXE  (MR*HID)        // x elems        6291456
#define NWE  (HID*HID)       // one W elems     589824

typedef unsigned short u16;
typedef u16   u16x8  __attribute__((ext_vector_type(8)));
typedef __bf16 bf16x8 __attribute__((ext_vector_type(8)));
typedef float f32x4  __attribute__((ext_vector_type(4)));

__device__ __forceinline__ float hi2f(unsigned u) {
    union { unsigned i; float f; } c; c.i = u & 0xffff0000u; return c.f;
}
__device__ __forceinline__ float lo2f(unsigned u) {
    union { unsigned i; float f; } c; c.i = u << 16; return c.f;
}
__device__ __forceinline__ u16 f2b(float f) {
    union { float f; unsigned i; } c; c.f = f;
    unsigned x = c.i + 0x7fffu + ((c.i >> 16) & 1u);   // RNE
    return (u16)(x >> 16);
}
__device__ __forceinline__ unsigned pk2(float lo, float hi) {
    float2 f; f.x = lo; f.y = hi;
    union { __hip_bfloat162 h; unsigned u; } c;
    c.h = __float22bfloat162_rn(f);
    return c.u;
}
__device__ __forceinline__ f32x4 mfma16(u16x8 a, u16x8 b, f32x4 c) {
    return __builtin_amdgcn_mfma_f32_16x16x32_bf16(
        __builtin_bit_cast(bf16x8, a), __builtin_bit_cast(bf16x8, b), c, 0, 0, 0);
}
__device__ __forceinline__ void g2l16(const u16* g, u16* l) {
    __builtin_amdgcn_global_load_lds(
        (const __attribute__((address_space(1))) void*)g,
        (__attribute__((address_space(3))) void*)l, 16, 0, 0);
}
// pi: stored-row permutation for K (inverse of fragment key map g)
__device__ __forceinline__ int kperm(int k) {
    return ((k >> 5) << 5) | (((k >> 2) & 1) << 4) | (((k >> 3) & 3) << 2) | (k & 3);
}

// -------- one-time fp32 -> bf16 conversion of x and the three W matrices ----
__global__ __launch_bounds__(256) void to_bf16(
    const float* __restrict__ x,  const float* __restrict__ Wq,
    const float* __restrict__ Wk, const float* __restrict__ Wv,
    u16* __restrict__ dst)
{
    const int NX4 = NXE / 4, NW4 = NWE / 4, NT4 = NX4 + 3 * NW4;
    for (int i = blockIdx.x * 256 + threadIdx.x; i < NT4; i += gridDim.x * 256) {
        const float* src; u16* d;
        if (i < NX4) { src = x + (size_t)i * 4; d = dst + (size_t)i * 4; }
        else {
            int j = i - NX4; int w = j / NW4; int r = j - w * NW4;
            const float* Ws = (w == 0) ? Wq : ((w == 1) ? Wk : Wv);
            src = Ws + (size_t)r * 4; d = dst + NXE + (size_t)w * NWE + (size_t)r * 4;
        }
        float4 f = *(const float4*)src;
        uint2 o; o.x = pk2(f.x, f.y); o.y = pk2(f.z, f.w);
        *(uint2*)d = o;
    }
}

// -------- QKV projection: 128x128 tile, global_load_lds staging -------------
// Epilogues bake attn's per-kt prep in once:
//   wsel 0 (Q): pre-scaled by 0.125/ln2;  wsel 1 (K): pi-permuted rows;
//   wsel 2 (V): transposed [b,h][d][s] via per-wave LDS transpose, 128B runs.
__global__ __launch_bounds__(256, 3) void qkv_proj(
    const u16* __restrict__ xb, const u16* __restrict__ Wb,
    const float* __restrict__ bq, const float* __restrict__ bk,
    const float* __restrict__ bv, u16* __restrict__ qkv)
{
    const int wsel = blockIdx.z;
    const u16* W = Wb + (size_t)wsel * NWE;
    const float* bias = (wsel == 0) ? bq : ((wsel == 1) ? bk : bv);
    u16* out = qkv + (size_t)wsel * MR * HID;

    const int m0 = blockIdx.x * 128, n0 = blockIdx.y * 128;
    // union: As(128x32)=4096 u16 | Bs=4096 u16  vs  Lt 4 waves x 64 x 72 =18432
    __shared__ __align__(16) u16 smem[18432];
    u16 (*As)[32] = (u16(*)[32])smem;
    u16 (*Bs)[32] = (u16(*)[32])(smem + 4096);

    const int tid  = threadIdx.x;
    const int lane = tid & 63, wid = tid >> 6;
    const int quad = lane >> 4, l16 = lane & 15;
    const int wm = wid >> 1, wn = wid & 1;

    const int rA = 2 * wid * 16 + (lane >> 2);
    const int colh = (lane & 3) * 8;
    const u16* gx0 = xb + (size_t)(m0 + rA) * HID + colh;
    const u16* gx1 = gx0 + (size_t)16 * HID;
    const u16* gw0 = W  + (size_t)(n0 + rA) * HID + colh;
    const u16* gw1 = gw0 + (size_t)16 * HID;
    u16* lA0 = smem + (2 * wid) * 512 + lane * 8;
    u16* lA1 = lA0 + 512;
    u16* lB0 = smem + 4096 + (2 * wid) * 512 + lane * 8;
    u16* lB1 = lB0 + 512;

    f32x4 acc[4][4] = {};

    for (int k0 = 0; k0 < HID; k0 += 32) {
        g2l16(gx0 + k0, lA0); g2l16(gx1 + k0, lA1);
        g2l16(gw0 + k0, lB0); g2l16(gw1 + k0, lB1);
        __syncthreads();
        u16x8 af[4], bf[4];
        #pragma unroll
        for (int i = 0; i < 4; i++) af[i] = *(const u16x8*)&As[wm * 64 + i * 16 + l16][quad * 8];
        #pragma unroll
        for (int j = 0; j < 4; j++) bf[j] = *(const u16x8*)&Bs[wn * 64 + j * 16 + l16][quad * 8];
        #pragma unroll
        for (int i = 0; i < 4; i++)
            #pragma unroll
            for (int j = 0; j < 4; j++)
                acc[i][j] = mfma16(af[i], bf[j], acc[i][j]);
        __syncthreads();
    }

    if (wsel == 2) {
        // per-wave transpose: Lt[d_local][s_local], then coalesced 128B runs
        u16* lt = smem + wid * 4608;   // [64][72]
        #pragma unroll
        for (int j = 0; j < 4; j++) {
            const int col = n0 + wn * 64 + j * 16 + l16;
            const float bb = bias[col];
            #pragma unroll
            for (int i = 0; i < 4; i++) {
                uint2 pk;
                pk.x = pk2(acc[i][j][0] + bb, acc[i][j][1] + bb);
                pk.y = pk2(acc[i][j][2] + bb, acc[i][j][3] + bb);
                *(uint2*)(lt + (j * 16 + l16) * 72 + i * 16 + quad * 4) = pk;
            }
        }
        __syncthreads();   // also orders u16 writes vs uint4 reads (aliasing)
        const int bidx = m0 >> 11;
        const int s0 = (m0 & 2047) + wm * 64;
        #pragma unroll
        for (int it = 0; it < 8; it++) {
            const int dl = it * 8 + (lane >> 3), sl = (lane & 7) * 8;
            uint4 w = *(const uint4*)(lt + dl * 72 + sl);
            const int col = n0 + wn * 64 + dl;
            const int hh = col >> 6, d = col & 63;
            *(uint4*)(out + ((size_t)(bidx * NH + hh) * HD + d) * SS + s0 + sl) = w;
        }
    } else {
        const float scale = (wsel == 0) ? 0.18033688f : 1.0f;   // 0.125/ln2 for Q
        #pragma unroll
        for (int j = 0; j < 4; j++) {
            const int col = n0 + wn * 64 + j * 16 + l16;
            const float bb = bias[col];
            #pragma unroll
            for (int i = 0; i < 4; i++)
                #pragma unroll
                for (int r = 0; r < 4; r++) {
                    int row = m0 + wm * 64 + i * 16 + quad * 4 + r;
                    if (wsel == 1) row = (row & ~63) | kperm(row & 63);
                    out[(size_t)row * HID + col] = f2b((acc[i][j][r] + bb) * scale);
                }
        }
    }
}

// -------- Flash attention, S^T form, double-buffered, MFMA denominator -----
// 1 barrier/kt; global loads run 1 full iteration ahead; QK acc init = -6
// (fixed-shift exp2 softmax); denominator = ones-MFMA over P^T fragments.
__global__ __launch_bounds__(256, 3) void attn(
    const u16* __restrict__ qkv, float* __restrict__ out)
{
    const int q0 = blockIdx.x * 128;
    const int h  = blockIdx.y;
    const int b  = blockIdx.z;

    const u16* qb  = qkv + (size_t)b * SS * HID + h * HD;
    const u16* kb  = qkv + (size_t)MR * HID + (size_t)b * SS * HID + h * HD;
    const u16* vtb = qkv + (size_t)2 * MR * HID + ((size_t)(b * NH + h) * HD) * SS;
    float*     ob  = out + (size_t)b * SS * HID + h * HD;

    __shared__ __align__(16) u16 Ks[2][64][72];
    __shared__ __align__(16) u16 Vt[2][64][72];

    const int tid  = threadIdx.x;
    const int lane = tid & 63, wid = tid >> 6;
    const int quad = lane >> 4, l16 = lane & 15;
    const int srow = tid >> 3, scg = tid & 7;
    const int rr0 = srow, rr1 = 32 + srow;

    u16x8 qf[2][2];
    #pragma unroll
    for (int t = 0; t < 2; t++) {
        const int row = q0 + t * 64 + wid * 16 + l16;
        #pragma unroll
        for (int hh = 0; hh < 2; hh++)
            qf[t][hh] = *(const u16x8*)(qb + (size_t)row * HID + hh * 32 + quad * 8);
    }

    u16x8 ones;
    #pragma unroll
    for (int e = 0; e < 8; e++) ones[e] = 0x3F80;   // bf16 1.0

    f32x4 o2[2][4] = {};
    f32x4 lacc[2] = {};

    uint4 kreg[2], vreg[2];
    // preload tile 0 -> LDS buf0; prefetch tile 1 into regs
    kreg[0] = *(const uint4*)(kb + (size_t)rr0 * HID + scg * 8);
    kreg[1] = *(const uint4*)(kb + (size_t)rr1 * HID + scg * 8);
    vreg[0] = *(const uint4*)(vtb + (size_t)rr0 * SS + scg * 8);
    vreg[1] = *(const uint4*)(vtb + (size_t)rr1 * SS + scg * 8);
    *(uint4*)&Ks[0][rr0][scg * 8] = kreg[0];
    *(uint4*)&Ks[0][rr1][scg * 8] = kreg[1];
    *(uint4*)&Vt[0][rr0][scg * 8] = vreg[0];
    *(uint4*)&Vt[0][rr1][scg * 8] = vreg[1];
    kreg[0] = *(const uint4*)(kb + (size_t)(64 + rr0) * HID + scg * 8);
    kreg[1] = *(const uint4*)(kb + (size_t)(64 + rr1) * HID + scg * 8);
    vreg[0] = *(const uint4*)(vtb + (size_t)rr0 * SS + 64 + scg * 8);
    vreg[1] = *(const uint4*)(vtb + (size_t)rr1 * SS + 64 + scg * 8);
    __syncthreads();

    for (int kt = 0; kt < SS / 64; kt++) {
        const int cur = kt & 1;

        u16x8 kf[4][2], vf[4][2];
        #pragma unroll
        for (int n = 0; n < 4; n++)
            #pragma unroll
            for (int hh = 0; hh < 2; hh++) {
                kf[n][hh] = *(const u16x8*)&Ks[cur][n * 16 + l16][hh * 32 + quad * 8];
                vf[n][hh] = *(const u16x8*)&Vt[cur][n * 16 + l16][hh * 32 + quad * 8];
            }

        if (kt < 31) {   // store tile kt+1 into the other buffer
            *(uint4*)&Ks[cur ^ 1][rr0][scg * 8] = kreg[0];
            *(uint4*)&Ks[cur ^ 1][rr1][scg * 8] = kreg[1];
            *(uint4*)&Vt[cur ^ 1][rr0][scg * 8] = vreg[0];
            *(uint4*)&Vt[cur ^ 1][rr1][scg * 8] = vreg[1];
        }
        if (kt < 30) {   // prefetch tile kt+2
            const int kn = (kt + 2) * 64;
            kreg[0] = *(const uint4*)(kb + (size_t)(kn + rr0) * HID + scg * 8);
            kreg[1] = *(const uint4*)(kb + (size_t)(kn + rr1) * HID + scg * 8);
            vreg[0] = *(const uint4*)(vtb + (size_t)rr0 * SS + kn + scg * 8);
            vreg[1] = *(const uint4*)(vtb + (size_t)rr1 * SS + kn + scg * 8);
        }

        unsigned pkd[2][4][2];
        #pragma unroll
        for (int t = 0; t < 2; t++)
            #pragma unroll
            for (int n = 0; n < 4; n++) {
                f32x4 s = {-6.f, -6.f, -6.f, -6.f};   // fixed softmax shift
                s = mfma16(kf[n][0], qf[t][0], s);
                s = mfma16(kf[n][1], qf[t][1], s);
                const float p0 = __builtin_amdgcn_exp2f(s[0]);
                const float p1 = __builtin_amdgcn_exp2f(s[1]);
                const float p2 = __builtin_amdgcn_exp2f(s[2]);
                const float p3 = __builtin_amdgcn_exp2f(s[3]);
                pkd[t][n][0] = pk2(p0, p1);
                pkd[t][n][1] = pk2(p2, p3);
            }

        #pragma unroll
        for (int t = 0; t < 2; t++) {
            union { u16x8 v; unsigned d[4]; } bf0, bf1;
            bf0.d[0] = pkd[t][0][0]; bf0.d[1] = pkd[t][0][1];
            bf0.d[2] = pkd[t][1][0]; bf0.d[3] = pkd[t][1][1];
            bf1.d[0] = pkd[t][2][0]; bf1.d[1] = pkd[t][2][1];
            bf1.d[2] = pkd[t][3][0]; bf1.d[3] = pkd[t][3][1];
            lacc[t] = mfma16(ones, bf0.v, lacc[t]);   // denominator colsums
            lacc[t] = mfma16(ones, bf1.v, lacc[t]);
            #pragma unroll
            for (int n2 = 0; n2 < 4; n2++) {
                o2[t][n2] = mfma16(vf[n2][0], bf0.v, o2[t][n2]);
                o2[t][n2] = mfma16(vf[n2][1], bf1.v, o2[t][n2]);
            }
        }
        if (kt < 31) __syncthreads();
    }

    #pragma unroll
    for (int t = 0; t < 2; t++) {
        const float inv = 1.f / lacc[t][0];   // all regs/rows hold the colsum
        const int q = q0 + t * 64 + wid * 16 + l16;
        #pragma unroll
        for (int n2 = 0; n2 < 4; n2++) {
            f32x4 w = o2[t][n2];
            w[0] *= inv; w[1] *= inv; w[2] *= inv; w[3] *= inv;
            *(f32x4*)(ob + (size_t)q * HID + n2 * 16 + quad * 4) = w;
        }
    }
}

extern "C" void kernel_launch(void* const* d_in, const int* in_sizes, int n_in,
                              void* d_out, int out_size, void* d_ws, size_t ws_size,
                              hipStream_t stream) {
    const float* x  = (const float*)d_in[0];
    const float* Wq = (const float*)d_in[1];
    const float* bq = (const float*)d_in[2];
    const float* Wk = (const float*)d_in[3];
    const float* bk = (const float*)d_in[4];
    const float* Wv = (const float*)d_in[5];
    const float* bv = (const float*)d_in[6];
    float* out = (float*)d_out;
    u16* qkv = (u16*)d_ws;               // 36 MB scratch: Q | K(perm) | V^T
    u16* cvt = (u16*)d_out;              // bf16 x|Wq|Wk|Wv staged in output buf

    to_bf16<<<1024, 256, 0, stream>>>(x, Wq, Wk, Wv, cvt);

    dim3 gp(MR / 128, HID / 128, 3);    // 64 x 6 x 3
    qkv_proj<<<gp, 256, 0, stream>>>(cvt, cvt + NXE, bq, bk, bv, qkv);

    dim3 ga(SS / 128, NH, NB);          // 16 x 12 x 4
    attn<<<ga, 256, 0, stream>>>(qkv, out);
}

// Round 11
// 184.859 us; speedup vs baseline: 1.3388x; 1.3388x over previous
//
#include <hip/hip_runtime.h>
#include <hip/hip_bf16.h>
#include <math.h>

#define NH   12
#define HD   64
#define HID  768
#define NB   4
#define SS   2048
#define MR   (NB*SS)   // 8192 rows

#define NXE  (MR*HID)        // x elems        6291456
#define NWE  (HID*HID)       // one W elems     589824

typedef unsigned short u16;
typedef u16   u16x8  __attribute__((ext_vector_type(8)));
typedef __bf16 bf16x8 __attribute__((ext_vector_type(8)));
typedef float f32x4  __attribute__((ext_vector_type(4)));

__device__ __forceinline__ u16 f2b(float f) {
    union { float f; unsigned i; } c; c.f = f;
    unsigned x = c.i + 0x7fffu + ((c.i >> 16) & 1u);   // RNE
    return (u16)(x >> 16);
}
__device__ __forceinline__ unsigned pk2(float lo, float hi) {
    float2 f; f.x = lo; f.y = hi;
    union { __hip_bfloat162 h; unsigned u; } c;
    c.h = __float22bfloat162_rn(f);
    return c.u;
}
__device__ __forceinline__ f32x4 mfma16(u16x8 a, u16x8 b, f32x4 c) {
    return __builtin_amdgcn_mfma_f32_16x16x32_bf16(
        __builtin_bit_cast(bf16x8, a), __builtin_bit_cast(bf16x8, b), c, 0, 0, 0);
}
__device__ __forceinline__ void g2l16(const u16* g, u16* l) {
    __builtin_amdgcn_global_load_lds(
        (const __attribute__((address_space(1))) void*)g,
        (__attribute__((address_space(3))) void*)l, 16, 0, 0);
}
// pi: stored-row permutation for K (inverse of fragment key map g)
__device__ __forceinline__ int kperm(int k) {
    return ((k >> 5) << 5) | (((k >> 2) & 1) << 4) | (((k >> 3) & 3) << 2) | (k & 3);
}

// -------- one-time fp32 -> bf16 conversion of x and the three W matrices ----
__global__ __launch_bounds__(256) void to_bf16(
    const float* __restrict__ x,  const float* __restrict__ Wq,
    const float* __restrict__ Wk, const float* __restrict__ Wv,
    u16* __restrict__ dst)
{
    const int NX4 = NXE / 4, NW4 = NWE / 4, NT4 = NX4 + 3 * NW4;
    for (int i = blockIdx.x * 256 + threadIdx.x; i < NT4; i += gridDim.x * 256) {
        const float* src; u16* d;
        if (i < NX4) { src = x + (size_t)i * 4; d = dst + (size_t)i * 4; }
        else {
            int j = i - NX4; int w = j / NW4; int r = j - w * NW4;
            const float* Ws = (w == 0) ? Wq : ((w == 1) ? Wk : Wv);
            src = Ws + (size_t)r * 4; d = dst + NXE + (size_t)w * NWE + (size_t)r * 4;
        }
        float4 f = *(const float4*)src;
        uint2 o; o.x = pk2(f.x, f.y); o.y = pk2(f.z, f.w);
        *(uint2*)d = o;
    }
}

// -------- QKV projection: 128x128 tile, BK=64 via dual pitch-32 sub-tiles ---
// g2l16 staging (contiguity-safe per sub-tile); 12 k-iters, 32 MFMA/barrier.
// Epilogues bake attn prep: Q pre-scaled 0.125/ln2; K pi-permuted rows;
// V transposed [b,h][d][s] via per-wave LDS transpose (coalesced 128B runs).
__global__ __launch_bounds__(256, 3) void qkv_proj(
    const u16* __restrict__ xb, const u16* __restrict__ Wb,
    const float* __restrict__ bq, const float* __restrict__ bk,
    const float* __restrict__ bv, u16* __restrict__ qkv)
{
    const int wsel = blockIdx.z;
    const u16* W = Wb + (size_t)wsel * NWE;
    const float* bias = (wsel == 0) ? bq : ((wsel == 1) ? bk : bv);
    u16* out = qkv + (size_t)wsel * MR * HID;

    const int m0 = blockIdx.x * 128, n0 = blockIdx.y * 128;
    // staging: As0|As1|Bs0|Bs1, each [128][32] = 4096 u16 (16384 total);
    // Lt union (V epilogue): 4 waves x [64][72] = 18432 u16
    __shared__ __align__(16) u16 smem[18432];

    const int tid  = threadIdx.x;
    const int lane = tid & 63, wid = tid >> 6;
    const int quad = lane >> 4, l16 = lane & 15;
    const int wm = wid >> 1, wn = wid & 1;

    const int rA = 2 * wid * 16 + (lane >> 2);   // chunk 2w rows; +16 = chunk 2w+1
    const int colh = (lane & 3) * 8;
    const u16* gx0 = xb + (size_t)(m0 + rA) * HID + colh;
    const u16* gx1 = gx0 + (size_t)16 * HID;
    const u16* gw0 = W  + (size_t)(n0 + rA) * HID + colh;
    const u16* gw1 = gw0 + (size_t)16 * HID;
    u16* lA = smem + (2 * wid) * 512 + lane * 8;   // chunk 2w dest in As0

    f32x4 acc[4][4] = {};

    for (int k0 = 0; k0 < HID; k0 += 64) {
        g2l16(gx0 + k0,      lA);            g2l16(gx1 + k0,      lA + 512);
        g2l16(gx0 + k0 + 32, lA + 4096);     g2l16(gx1 + k0 + 32, lA + 4608);
        g2l16(gw0 + k0,      lA + 8192);     g2l16(gw1 + k0,      lA + 8704);
        g2l16(gw0 + k0 + 32, lA + 12288);    g2l16(gw1 + k0 + 32, lA + 12800);
        __syncthreads();
        #pragma unroll
        for (int hh = 0; hh < 2; hh++) {
            u16x8 af[4], bf[4];
            #pragma unroll
            for (int i = 0; i < 4; i++)
                af[i] = *(const u16x8*)(smem + hh * 4096 + (wm * 64 + i * 16 + l16) * 32 + quad * 8);
            #pragma unroll
            for (int j = 0; j < 4; j++)
                bf[j] = *(const u16x8*)(smem + 8192 + hh * 4096 + (wn * 64 + j * 16 + l16) * 32 + quad * 8);
            #pragma unroll
            for (int i = 0; i < 4; i++)
                #pragma unroll
                for (int j = 0; j < 4; j++)
                    acc[i][j] = mfma16(af[i], bf[j], acc[i][j]);
        }
        __syncthreads();
    }

    if (wsel == 2) {
        // per-wave transpose: Lt[d_local][s_local], then coalesced 128B runs
        u16* lt = smem + wid * 4608;   // [64][72]
        #pragma unroll
        for (int j = 0; j < 4; j++) {
            const int col = n0 + wn * 64 + j * 16 + l16;
            const float bb = bias[col];
            #pragma unroll
            for (int i = 0; i < 4; i++) {
                uint2 pk;
                pk.x = pk2(acc[i][j][0] + bb, acc[i][j][1] + bb);
                pk.y = pk2(acc[i][j][2] + bb, acc[i][j][3] + bb);
                *(uint2*)(lt + (j * 16 + l16) * 72 + i * 16 + quad * 4) = pk;
            }
        }
        __syncthreads();
        const int bidx = m0 >> 11;
        const int s0 = (m0 & 2047) + wm * 64;
        #pragma unroll
        for (int it = 0; it < 8; it++) {
            const int dl = it * 8 + (lane >> 3), sl = (lane & 7) * 8;
            uint4 w = *(const uint4*)(lt + dl * 72 + sl);
            const int col = n0 + wn * 64 + dl;
            const int hh = col >> 6, d = col & 63;
            *(uint4*)(out + ((size_t)(bidx * NH + hh) * HD + d) * SS + s0 + sl) = w;
        }
    } else {
        const float scale = (wsel == 0) ? 0.18033688f : 1.0f;   // 0.125/ln2 for Q
        #pragma unroll
        for (int j = 0; j < 4; j++) {
            const int col = n0 + wn * 64 + j * 16 + l16;
            const float bb = bias[col];
            #pragma unroll
            for (int i = 0; i < 4; i++)
                #pragma unroll
                for (int r = 0; r < 4; r++) {
                    int row = m0 + wm * 64 + i * 16 + quad * 4 + r;
                    if (wsel == 1) row = (row & ~63) | kperm(row & 63);
                    out[(size_t)row * HID + col] = f2b((acc[i][j][r] + bb) * scale);
                }
        }
    }
}

// -------- Flash attention: XCD-swizzled grid, g2l16 LDS double-buffer -------
// 1D grid: lin%8 = XCD residue; all 16 q-tiles of a (b,h) share one XCD ->
// K/V (512 KB/pair, 6 pairs = 3 MB/XCD) stays L2-resident (~37 TB/s) instead
// of 16x L3 re-reads. Staging via global_load_lds into alternating LDS buffers
// (no VGPRs -> no R10 spills); prefetch issued before compute each iter.
// Fixed-shift softmax (QK acc init -6), denominator via ones-MFMA (R10-verified).
__global__ __launch_bounds__(256, 3) void attn(
    const u16* __restrict__ qkv, float* __restrict__ out)
{
    const int lin = blockIdx.x;          // 0..767
    const int rx  = lin & 7;             // XCD residue
    const int gg  = lin >> 3;            // 0..95
    const int qt  = gg & 15;
    const int bh  = rx * 6 + (gg >> 4);  // 0..47
    const int b   = bh / NH, h = bh - b * NH;
    const int q0  = qt * 128;

    const u16* qb  = qkv + (size_t)b * SS * HID + h * HD;
    const u16* kb  = qkv + (size_t)MR * HID + (size_t)b * SS * HID + h * HD;
    const u16* vtb = qkv + (size_t)2 * MR * HID + ((size_t)(b * NH + h) * HD) * SS;
    float*     ob  = out + (size_t)b * SS * HID + h * HD;

    // [buf][hh][64 rows][32 cols]: flat for g2l16 lane-contiguity
    __shared__ __align__(16) u16 KS[2][2][2048];
    __shared__ __align__(16) u16 VS[2][2][2048];

    const int tid  = threadIdx.x;
    const int lane = tid & 63, wid = tid >> 6;
    const int quad = lane >> 4, l16 = lane & 15;

    // staging addresses: wave w -> rows 16w..16w+15 of each sub-tile
    const int srow = 16 * wid + (lane >> 2);
    const int sc8  = (lane & 3) * 8;
    const int ldst = wid * 512 + lane * 8;

    u16x8 qf[2][2];
    #pragma unroll
    for (int t = 0; t < 2; t++) {
        const int row = q0 + t * 64 + wid * 16 + l16;
        #pragma unroll
        for (int hh = 0; hh < 2; hh++)
            qf[t][hh] = *(const u16x8*)(qb + (size_t)row * HID + hh * 32 + quad * 8);
    }

    u16x8 ones;
    #pragma unroll
    for (int e = 0; e < 8; e++) ones[e] = 0x3F80;   // bf16 1.0

    f32x4 o2[2][4] = {};
    f32x4 lacc[2] = {};

    // stage tile 0 into buf 0
    {
        const u16* kg = kb + (size_t)srow * HID + sc8;
        const u16* vg = vtb + (size_t)srow * SS + sc8;
        g2l16(kg, &KS[0][0][0] + ldst);  g2l16(kg + 32, &KS[0][1][0] + ldst);
        g2l16(vg, &VS[0][0][0] + ldst);  g2l16(vg + 32, &VS[0][1][0] + ldst);
    }
    __syncthreads();

    for (int kt = 0; kt < SS / 64; kt++) {
        const int cur = kt & 1;

        if (kt < 31) {   // async prefetch of tile kt+1 into the other buffer
            const int kn = (kt + 1) * 64;
            const u16* kg = kb + (size_t)(kn + srow) * HID + sc8;
            const u16* vg = vtb + (size_t)srow * SS + kn + sc8;
            g2l16(kg, &KS[cur ^ 1][0][0] + ldst);  g2l16(kg + 32, &KS[cur ^ 1][1][0] + ldst);
            g2l16(vg, &VS[cur ^ 1][0][0] + ldst);  g2l16(vg + 32, &VS[cur ^ 1][1][0] + ldst);
        }

        u16x8 kf[4][2];
        #pragma unroll
        for (int n = 0; n < 4; n++)
            #pragma unroll
            for (int hh = 0; hh < 2; hh++)
                kf[n][hh] = *(const u16x8*)(&KS[cur][hh][0] + (n * 16 + l16) * 32 + quad * 8);

        unsigned pkd[2][4][2];
        #pragma unroll
        for (int t = 0; t < 2; t++)
            #pragma unroll
            for (int n = 0; n < 4; n++) {
                f32x4 s = {-6.f, -6.f, -6.f, -6.f};   // fixed softmax shift
                s = mfma16(kf[n][0], qf[t][0], s);
                s = mfma16(kf[n][1], qf[t][1], s);
                const float p0 = __builtin_amdgcn_exp2f(s[0]);
                const float p1 = __builtin_amdgcn_exp2f(s[1]);
                const float p2 = __builtin_amdgcn_exp2f(s[2]);
                const float p3 = __builtin_amdgcn_exp2f(s[3]);
                pkd[t][n][0] = pk2(p0, p1);
                pkd[t][n][1] = pk2(p2, p3);
            }

        u16x8 vf[4][2];
        #pragma unroll
        for (int n2 = 0; n2 < 4; n2++)
            #pragma unroll
            for (int hh = 0; hh < 2; hh++)
                vf[n2][hh] = *(const u16x8*)(&VS[cur][hh][0] + (n2 * 16 + l16) * 32 + quad * 8);

        #pragma unroll
        for (int t = 0; t < 2; t++) {
            union { u16x8 v; unsigned d[4]; } bf0, bf1;
            bf0.d[0] = pkd[t][0][0]; bf0.d[1] = pkd[t][0][1];
            bf0.d[2] = pkd[t][1][0]; bf0.d[3] = pkd[t][1][1];
            bf1.d[0] = pkd[t][2][0]; bf1.d[1] = pkd[t][2][1];
            bf1.d[2] = pkd[t][3][0]; bf1.d[3] = pkd[t][3][1];
            lacc[t] = mfma16(ones, bf0.v, lacc[t]);   // denominator colsums
            lacc[t] = mfma16(ones, bf1.v, lacc[t]);
            #pragma unroll
            for (int n2 = 0; n2 < 4; n2++) {
                o2[t][n2] = mfma16(vf[n2][0], bf0.v, o2[t][n2]);
                o2[t][n2] = mfma16(vf[n2][1], bf1.v, o2[t][n2]);
            }
        }
        __syncthreads();   // readers done + prefetch writes drained
    }

    #pragma unroll
    for (int t = 0; t < 2; t++) {
        const float inv = 1.f / lacc[t][0];   // all regs hold the q=l16 colsum
        const int q = q0 + t * 64 + wid * 16 + l16;
        #pragma unroll
        for (int n2 = 0; n2 < 4; n2++) {
            f32x4 w = o2[t][n2];
            w[0] *= inv; w[1] *= inv; w[2] *= inv; w[3] *= inv;
            *(f32x4*)(ob + (size_t)q * HID + n2 * 16 + quad * 4) = w;
        }
    }
}

extern "C" void kernel_launch(void* const* d_in, const int* in_sizes, int n_in,
                              void* d_out, int out_size, void* d_ws, size_t ws_size,
                              hipStream_t stream) {
    const float* x  = (const float*)d_in[0];
    const float* Wq = (const float*)d_in[1];
    const float* bq = (const float*)d_in[2];
    const float* Wk = (const float*)d_in[3];
    const float* bk = (const float*)d_in[4];
    const float* Wv = (const float*)d_in[5];
    const float* bv = (const float*)d_in[6];
    float* out = (float*)d_out;
    u16* qkv = (u16*)d_ws;               // 36 MB scratch: Q | K(perm) | V^T
    u16* cvt = (u16*)d_out;              // bf16 x|Wq|Wk|Wv staged in output buf

    to_bf16<<<1024, 256, 0, stream>>>(x, Wq, Wk, Wv, cvt);

    dim3 gp(MR / 128, HID / 128, 3);    // 64 x 6 x 3
    qkv_proj<<<gp, 256, 0, stream>>>(cvt, cvt + NXE, bq, bk, bv, qkv);

    attn<<<768, 256, 0, stream>>>(qkv, out);   // 1D, XCD-swizzled
}